// Round 5
// baseline (655.335 us; speedup 1.0000x reference)
//
#include <hip/hip_runtime.h>
#include <hip/hip_bf16.h>
#include <hip/hip_cooperative_groups.h>

namespace cg = cooperative_groups;

#define N_NODES 50000
#define N_EDGES 1000000
#define C       128
#define N_REL   8
#define N_SEG   (N_NODES * N_REL)       // 400000
#define KTOT    (N_REL * C + C)         // 1152 = 8 rel chunks + self
#define KC_CNT  (KTOT / 32)             // 36 MFMA k-chunks
#define A_STRIDE 1160                   // 1152 + 8 bf16 pad per row
#define NCHUNK  ((N_SEG + 1023) / 1024) // 391 scan chunks
#define MV_N    (N_SEG + 1 + N_EDGES)   // 1,400,001 ints to relocate
#define NBLK    (N_NODES / 16)          // 3125 layer tiles
#define RPB1    (KTOT * C / 512)        // 288 repack1 vblocks (512 thr)
#define RPT_B   ((KTOT / 16) * (C / 16))// 576 repack2 tiles
#define P2_VB   (NCHUNK + RPB1 + RPT_B + 1)   // 1256 virtual blocks in phase 2

typedef __hip_bfloat16  bf16;
typedef __hip_bfloat162 bf162;
typedef __attribute__((ext_vector_type(8))) short short8;
typedef __attribute__((ext_vector_type(4))) float f32x4;

// ---------------------------------------------------------------- weight fragment index
// B-fragment for mfma_f32_16x16x32_bf16: lane = quad*16 + (n&15) holds
// B[k = kc*32 + quad*8 + j][n], j=0..7 contiguous.
__device__ __forceinline__ size_t frag_index(int k, int n) {
    int nt = n >> 4, n15 = n & 15;
    int kc = k >> 5, quad = (k >> 3) & 3, j = k & 7;
    int lane = quad * 16 + n15;
    return ((size_t)(nt * KC_CNT + kc) * 64 + lane) * 8 + j;
}

// ---------------------------------------------------------------- BUILD (cooperative)
// R15: one dispatch replaces memset+prep+scanA+fillB (theory: ~10us/launch
// overhead dominates the CSR chain; in-kernel work only ~90us of its 150us).
// P0: zero cnt + x->bf16 cvt
// P1: count atomics; pack (rank<<19 | seg) -> rankseg  (seg<2^19, rank<2^13)
// P2: chunk-local scans (+partials) and weight repacks (virtual blocks)
// P3: per-block partials scan in LDS; edge placement; block0 publishes spx
__global__ __launch_bounds__(512, 8) void build_kernel(
        const float2* __restrict__ xf, unsigned int* __restrict__ xb,
        const int* __restrict__ src, const int* __restrict__ dst, const int* __restrict__ et,
        int* __restrict__ cnt, int* __restrict__ rankseg,
        int* __restrict__ offs, int* __restrict__ partials, int* __restrict__ spx,
        const float* __restrict__ W1, const float* __restrict__ root1,
        const float* __restrict__ W2, const float* __restrict__ root2,
        const float* __restrict__ linW, const float* __restrict__ b2v,
        const float* __restrict__ linb,
        bf16* __restrict__ Bp1, bf16* __restrict__ Bp2, float* __restrict__ b2p,
        int* __restrict__ srcs_out)
{
    cg::grid_group gg = cg::this_grid();
    __shared__ __align__(16) char smem[16384];
    const int t = threadIdx.x, bid = blockIdx.x, nb = gridDim.x;
    const int gtid = bid * 512 + t, gstr = nb * 512;

    // ---- P0: zero counters + convert x to bf16 pairs
    for (int i = gtid; i < N_SEG; i += gstr) cnt[i] = 0;
    for (int i = gtid; i < N_NODES * C / 2; i += gstr) {
        float2 v = xf[i];
        union { bf162 h; unsigned int u; } cv;
        cv.h = bf162(__float2bfloat16(v.x), __float2bfloat16(v.y));
        xb[i] = cv.u;
    }
    gg.sync();

    // ---- P1: per-segment counts; atomic return value IS the rank
    for (int e = gtid; e < N_EDGES; e += gstr) {
        int seg = dst[e] * N_REL + et[e];
        int r = atomicAdd(&cnt[seg], 1);
        rankseg[e] = (r << 19) | seg;
    }
    gg.sync();

    // ---- P2: chunk scans + weight repacks (grid-stride over virtual blocks)
    {
        int* tot = (int*)smem;
        for (int vb = bid; vb < P2_VB; vb += nb) {
            if (vb < NCHUNK) {
                int base = vb * 1024 + t * 2;
                int v0 = (base < N_SEG) ? cnt[base] : 0;
                int v1 = (base + 1 < N_SEG) ? cnt[base + 1] : 0;
                int ts = v0 + v1;
                tot[t] = ts;
                __syncthreads();
                for (int d = 1; d < 512; d <<= 1) {
                    int x = tot[t];
                    int y = (t >= d) ? tot[t - d] : 0;
                    __syncthreads();
                    tot[t] = x + y;
                    __syncthreads();
                }
                int excl = tot[t] - ts;
                if (base < N_SEG)     offs[base]     = excl;
                if (base + 1 < N_SEG) offs[base + 1] = excl + v0;
                if (t == 511) partials[vb] = tot[511];
            } else if (vb < NCHUNK + RPB1) {
                int idx = (vb - NCHUNK) * 512 + t;
                int k = idx >> 7, n = idx & 127;
                float val;
                if (k < N_REL * C) val = W1[(size_t)k * C + n];
                else               val = root1[(size_t)(k - N_REL * C) * C + n];
                Bp1[frag_index(k, n)] = __float2bfloat16(val);
            } else if (vb < NCHUNK + RPB1 + RPT_B) {
                // tiled repack2: out(k0+ty, n0+tx) = sum_m W2cat[k0+ty][m]*linW[m][n0+tx]
                float (*Wt)[128] = (float (*)[128])smem;          // 8 KB
                float (*Lt)[16]  = (float (*)[16])(smem + 8192);  // 8 KB
                int tileid = vb - NCHUNK - RPB1;
                int kt = tileid >> 3;
                int n0 = (tileid & 7) * 16;
                int k0 = kt * 16;
                const float* baseW = (k0 < N_REL * C) ? (W2 + (size_t)k0 * C)
                                                      : (root2 + (size_t)(k0 - N_REL * C) * C);
#pragma unroll
                for (int r = 0; r < 4; r++) {             // 2048 elems, coalesced
                    int idx = t + r * 512;
                    Wt[idx >> 7][idx & 127] = baseW[idx];
                }
#pragma unroll
                for (int r = 0; r < 4; r++) {             // 2048 elems
                    int idx = t + r * 512;
                    Lt[idx >> 4][idx & 15] = linW[(size_t)(idx >> 4) * C + n0 + (idx & 15)];
                }
                __syncthreads();
                if (t < 256) {
                    int ty = t >> 4, tx = t & 15;
                    float acc = 0.f;
#pragma unroll 8
                    for (int m = 0; m < 128; m++)
                        acc += Wt[ty][m] * Lt[m][tx];
                    Bp2[frag_index(k0 + ty, n0 + tx)] = __float2bfloat16(acc);
                }
            } else {
                if (t < 128) {
                    float acc = linb[t];
                    for (int m = 0; m < C; m++)
                        acc += b2v[m] * linW[(size_t)m * C + t];
                    b2p[t] = acc;
                }
            }
            __syncthreads();   // protect smem reuse across virtual blocks
        }
    }
    gg.sync();

    // ---- P3: partials scan (every block, in LDS) + edge placement
    {
        int* s = (int*)smem;
        s[t] = (t < NCHUNK) ? partials[t] : 0;
        __syncthreads();
        for (int d = 1; d < 512; d <<= 1) {
            int x = s[t];
            int y = (t >= d) ? s[t - d] : 0;
            __syncthreads();
            s[t] = x + y;          // inclusive scan
            __syncthreads();
        }
        if (bid == 0 && t < NCHUNK) spx[t] = (t == 0) ? 0 : s[t - 1];
        for (int e = gtid; e < N_EDGES; e += gstr) {
            int rs = rankseg[e];
            int seg = rs & 0x7FFFF;
            int r = ((unsigned int)rs) >> 19;
            int chunk = seg >> 10;
            int base = offs[seg] + ((chunk == 0) ? 0 : s[chunk - 1]);
            srcs_out[base + r] = src[e];
        }
    }
}

// ---------------------------------------------------------------- fused layer tile body
// R0-proven body (73.4 us/layer measured), verbatim: 16 nodes/tile, 8 waves,
// wave w owns segments [16w,16w+16), explicit 2-stage gather pipeline, LDS
// offsL. Trailing __syncthreads protects LDS reuse across grid-stride tiles.
template <int RELU, int OUT_F32, int RAWOFFS>
__device__ __forceinline__ void layer_tile(
        int tileid,
        const unsigned int* __restrict__ featu,  // [N][64] bf16 pairs
        const int*   __restrict__ offs,          // raw (RAWOFFS=1) or final (0)
        const int*   __restrict__ srcs,          // [N_EDGES]
        const short8* __restrict__ Bp,           // fragment-packed bf16 weights
        const float* __restrict__ bias,          // [128] fp32
        void* __restrict__ outp,                 // [N][128] fp32 or bf16
        const int* __restrict__ spx,             // [NCHUNK] chunk prefix (RAWOFFS=1)
        unsigned int* At, int* offsL)
{
    const int tid  = threadIdx.x;
    const int lane = tid & 63;
    const int w    = tid >> 6;          // 0..7
    const int v0   = tileid * 16;

    if (tid < 129) {
        int idx = v0 * 8 + tid;
        int val;
        if (RAWOFFS) val = (idx < N_SEG) ? offs[idx] + spx[idx >> 10] : N_EDGES;
        else         val = offs[idx];
        offsL[tid] = val;
    }
    if (tid < 64)  At[(tid >> 2) * (A_STRIDE / 2) + 576 + (tid & 3)] = 0u;  // pad pairs

    // self rows -> k range [1024..1151]
    for (int q = tid; q < 16 * 64; q += 512) {
        int node = q >> 6, pch = q & 63;
        At[node * (A_STRIDE / 2) + 512 + pch] = featu[(size_t)(v0 + node) * 64 + pch];
    }
    __syncthreads();

    // ---- aggregation over wave-owned contiguous edge range (16 segments)
    {
        const int segLo = w * 16;
        const int segHi = segLo + 16;
        int curSeg = segLo;
        int segEnd = offsL[curSeg + 1];
        int i      = offsL[segLo];
        const int eend = offsL[segHi];
        float a0 = 0.f, a1 = 0.f;

        unsigned int vals[16];
        bool have = (i + 16 <= eend);
        if (have) {
            const int ib = __builtin_amdgcn_readfirstlane(i);
            int sv[16];
#pragma unroll
            for (int j = 0; j < 16; j++) sv[j] = srcs[ib + j];
#pragma unroll
            for (int j = 0; j < 16; j++) vals[j] = featu[(size_t)sv[j] * 64 + lane];
        }
        while (have) {
            const int inext = i + 16;
            const bool havenext = (inext + 16 <= eend);
            unsigned int vals2[16];
            if (havenext) {                       // prefetch batch k+1 (straight-line)
                const int ib2 = __builtin_amdgcn_readfirstlane(inext);
                int sv2[16];
#pragma unroll
                for (int j = 0; j < 16; j++) sv2[j] = srcs[ib2 + j];
#pragma unroll
                for (int j = 0; j < 16; j++) vals2[j] = featu[(size_t)sv2[j] * 64 + lane];
            }
            // fold batch k
#pragma unroll
            for (int j = 0; j < 16; j++) {
                while (i + j == segEnd) {         // flush finished segment(s)
                    int b = offsL[curSeg];
                    float inv = (segEnd > b) ? 1.0f / (float)(segEnd - b) : 0.0f;
                    union { bf162 h; unsigned int u; } cv;
                    cv.h = bf162(__float2bfloat16(a0 * inv), __float2bfloat16(a1 * inv));
                    At[(curSeg >> 3) * (A_STRIDE / 2) + (curSeg & 7) * 64 + lane] = cv.u;
                    a0 = 0.f; a1 = 0.f;
                    curSeg++;
                    segEnd = offsL[curSeg + 1];
                }
                union { bf162 h; unsigned int u; } uv; uv.u = vals[j];
                a0 += __low2float(uv.h);
                a1 += __high2float(uv.h);
            }
            i = inext;
            have = havenext;
            if (havenext) {
#pragma unroll
                for (int j = 0; j < 16; j++) vals[j] = vals2[j];
            }
        }
        // predicated tail batch (m < 16, wave-uniform)
        {
            int m = eend - i;
            const int ib = __builtin_amdgcn_readfirstlane(i);
            int sv[16];
#pragma unroll
            for (int j = 0; j < 16; j++) if (j < m) sv[j] = srcs[ib + j];
            unsigned int tvals[16];
#pragma unroll
            for (int j = 0; j < 16; j++) if (j < m) tvals[j] = featu[(size_t)sv[j] * 64 + lane];
#pragma unroll
            for (int j = 0; j < 16; j++) {
                if (j < m) {
                    while (i + j == segEnd) {
                        int b = offsL[curSeg];
                        float inv = (segEnd > b) ? 1.0f / (float)(segEnd - b) : 0.0f;
                        union { bf162 h; unsigned int u; } cv;
                        cv.h = bf162(__float2bfloat16(a0 * inv), __float2bfloat16(a1 * inv));
                        At[(curSeg >> 3) * (A_STRIDE / 2) + (curSeg & 7) * 64 + lane] = cv.u;
                        a0 = 0.f; a1 = 0.f;
                        curSeg++;
                        segEnd = offsL[curSeg + 1];
                    }
                    union { bf162 h; unsigned int u; } uv; uv.u = tvals[j];
                    a0 += __low2float(uv.h);
                    a1 += __high2float(uv.h);
                }
            }
        }
        // trailing flushes (last non-empty segment + empty tails)
        while (curSeg < segHi) {
            int b = offsL[curSeg], e2 = offsL[curSeg + 1];
            float inv = (e2 > b) ? 1.0f / (float)(e2 - b) : 0.0f;
            union { bf162 h; unsigned int u; } cv;
            cv.h = bf162(__float2bfloat16(a0 * inv), __float2bfloat16(a1 * inv));
            At[(curSeg >> 3) * (A_STRIDE / 2) + (curSeg & 7) * 64 + lane] = cv.u;
            a0 = 0.f; a1 = 0.f;
            curSeg++;
        }
    }
    __syncthreads();

    // ---- MFMA GEMM: wave w computes N-tile w (cols 16w..16w+15)
    const int quad = lane >> 4, n15 = lane & 15;
    f32x4 acc = {0.f, 0.f, 0.f, 0.f};
    const short* Ash = (const short*)At;

    short8 b0 = Bp[(size_t)(w * KC_CNT) * 64 + lane];
#pragma unroll 4
    for (int kc = 0; kc < KC_CNT; kc++) {
        short8 cb0 = b0;
        if (kc + 1 < KC_CNT)
            b0 = Bp[(size_t)(w * KC_CNT + kc + 1) * 64 + lane];
        short8 a = *reinterpret_cast<const short8*>(Ash + n15 * A_STRIDE + kc * 32 + quad * 8);
        acc = __builtin_amdgcn_mfma_f32_16x16x32_bf16(a, cb0, acc, 0, 0, 0);
    }

    // epilogue: D[m = quad*4 + r][col = w*16 + n15]
    {
        int col = w * 16 + n15;
        float bv = bias[col];
#pragma unroll
        for (int r = 0; r < 4; r++) {
            int m = quad * 4 + r;
            float v = acc[r] + bv;
            if (RELU) v = fmaxf(v, 0.f);
            if (OUT_F32) ((float*)outp)[(size_t)(v0 + m) * C + col] = v;
            else         ((bf16*)outp)[(size_t)(v0 + m) * C + col] = __float2bfloat16(v);
        }
    }
    __syncthreads();   // protect LDS reuse across grid-stride tiles
}

// ---------------------------------------------------------------- FUSED (cooperative)
// Layer 1 (grid-stride tiles) -> grid.sync -> layer 2. The CSR copy to the ei
// buffer (finalized offsets) runs once per block before layer-1 tiles.
__global__ __launch_bounds__(512, 8) void fused2_kernel(
        const unsigned int* __restrict__ xb16,
        const int* __restrict__ offs_raw, const int* __restrict__ srcs_t,
        const short8* __restrict__ Bp1, const float* __restrict__ b1,
        unsigned int* __restrict__ h1,
        int* __restrict__ offs2, int* __restrict__ srcs2,
        const int* __restrict__ spx,
        const short8* __restrict__ Bp2, const float* __restrict__ b2p,
        float* __restrict__ out)
{
    cg::grid_group gg = cg::this_grid();
    __shared__ __align__(16) unsigned int At[16 * (A_STRIDE / 2)];
    __shared__ int offsL[129];
    const int bid = blockIdx.x, nb = gridDim.x, tid = threadIdx.x;

    // relocate CSR (finalized) out of d_out before layer 2 overwrites it
    for (int i = bid * 512 + tid; i < MV_N; i += nb * 512) {
        if (i < N_SEG + 1) offs2[i] = (i < N_SEG) ? offs_raw[i] + spx[i >> 10] : N_EDGES;
        else               srcs2[i - (N_SEG + 1)] = srcs_t[i - (N_SEG + 1)];
    }

    for (int tile = bid; tile < NBLK; tile += nb)
        layer_tile<1, 0, 1>(tile, xb16, offs_raw, srcs_t, Bp1, b1, (void*)h1, spx, At, offsL);

    gg.sync();

    for (int tile = bid; tile < NBLK; tile += nb)
        layer_tile<0, 1, 0>(tile, h1, offs2, srcs2, Bp2, b2p, (void*)out, nullptr, At, offsL);
}

// ---------------------------------------------------------------- launch
// fp32 I/O. ZERO d_ws usage. Provenance:
//   d_out lo   : CSR scratch (cnt / offs_t raw / partials / spx / srcs / rankseg)
//   d_out hi   : x as bf16 (12.8 MB @ +11,203,584, 256B-ALIGNED) [dead after layer 1]
//   x buffer lo: h1 bf16 (12.8 MB)                            [x fp32 dead after P0 cvt]
//   x buffer hi: packed weights Bp1/Bp2/b2p (@ +13.0 MB)      [written in BUILD P2]
//   ei buffer  : final CSR (offs2+srcs2), copied+finalized BY fused layer 1
//   d_out      : final fp32 output (layer 2 writes directly)
extern "C" void kernel_launch(void* const* d_in, const int* in_sizes, int n_in,
                              void* d_out, int out_size, void* d_ws, size_t ws_size,
                              hipStream_t stream) {
    const float* x     = (const float*)d_in[0];
    const int*   ei    = (const int*)d_in[1];
    const int*   et    = (const int*)d_in[2];
    const float* W1    = (const float*)d_in[3];
    const float* root1 = (const float*)d_in[4];
    const float* b1    = (const float*)d_in[5];
    const float* W2    = (const float*)d_in[6];
    const float* root2 = (const float*)d_in[7];
    const float* b2    = (const float*)d_in[8];
    const float* linW  = (const float*)d_in[9];
    const float* linb  = (const float*)d_in[10];
    const int* src = ei;
    const int* dst = ei + N_EDGES;

    // ---- d_out scratch
    char* ob = (char*)d_out;
    int* cnt_i    = (int*)(ob + 0);          // 1,600,000 B (zeroed in BUILD P0)
    int* offs_t   = (int*)(ob + 1600000);    // 1,600,000 B (raw chunk-local scans)
    int* partials = (int*)(ob + 3200000);    // 1,564 B
    int* spx      = (int*)(ob + 3201792);    // 1,564 B (exclusive chunk prefix)
    int* srcs_t   = (int*)(ob + 3203584);    // 4,000,000 B -> ends 7,203,584
    int* rankseg  = (int*)(ob + 7203584);    // 4,000,000 B -> ends 11,203,584
    unsigned int* xb16 = (unsigned int*)(ob + 11203584); // ends 24,003,584 < 25.6 MB

    // ---- ei buffer: final CSR (written by fused layer 1's copy slice)
    char* eb = (char*)d_in[1];
    int* offs2 = (int*)(eb + 0);
    int* srcs2 = (int*)(eb + 1600256);       // ends 5,600,256 < 8 MB

    // ---- x buffer: h1 low, weights high
    char* xbuf = (char*)d_in[0];
    unsigned int* h1 = (unsigned int*)xbuf;          // 12.8 MB
    bf16*  Bp1 = (bf16*)(xbuf + 13000192);           // 16B-aligned, 294,912 B
    bf16*  Bp2 = (bf16*)(xbuf + 13295360);           // 294,912 B
    float* b2p = (float*)(xbuf + 13590528);          // 512 B -> ends < 25.6 MB

    float* out = (float*)d_out;

    // ---- cooperative grid sizing (computed once; pure queries, capture-safe)
    static int gridB = 0, gridF = 0;
    if (gridF == 0) {
        int dev = 0;
        hipGetDevice(&dev);
        hipDeviceProp_t prop;
        hipGetDeviceProperties(&prop, dev);
        int nCU = prop.multiProcessorCount;
        if (nCU <= 0) nCU = 256;
        int occB = 0, occF = 0;
        hipOccupancyMaxActiveBlocksPerMultiprocessor(&occB, (const void*)build_kernel, 512, 0);
        hipOccupancyMaxActiveBlocksPerMultiprocessor(&occF, (const void*)fused2_kernel, 512, 0);
        if (occB < 1) occB = 1;
        if (occF < 1) occF = 1;
        gridB = occB * nCU;
        if (gridB > 2048) gridB = 2048;
        int maxF = occF * nCU;
        int tpb  = (NBLK + maxF - 1) / maxF;     // tiles per block (uniform)
        gridF = (NBLK + tpb - 1) / tpb;          // minimal grid achieving that
    }

    // ---- launch 1: BUILD
    const float2* xf = (const float2*)x;
    void* argsB[] = {
        (void*)&xf, (void*)&xb16, (void*)&src, (void*)&dst, (void*)&et,
        (void*)&cnt_i, (void*)&rankseg, (void*)&offs_t, (void*)&partials, (void*)&spx,
        (void*)&W1, (void*)&root1, (void*)&W2, (void*)&root2, (void*)&linW,
        (void*)&b2, (void*)&linb, (void*)&Bp1, (void*)&Bp2, (void*)&b2p,
        (void*)&srcs_t };
    hipLaunchCooperativeKernel((const void*)build_kernel, dim3(gridB), dim3(512),
                               argsB, 0, stream);

    // ---- launch 2: FUSED (both layers)
    const short8* Bp1v = (const short8*)Bp1;
    const short8* Bp2v = (const short8*)Bp2;
    void* argsF[] = {
        (void*)&xb16, (void*)&offs_t, (void*)&srcs_t,
        (void*)&Bp1v, (void*)&b1, (void*)&h1,
        (void*)&offs2, (void*)&srcs2, (void*)&spx,
        (void*)&Bp2v, (void*)&b2p, (void*)&out };
    hipLaunchCooperativeKernel((const void*)fused2_kernel, dim3(gridF), dim3(512),
                               argsF, 0, stream);

    (void)in_sizes; (void)n_in; (void)out_size; (void)d_ws; (void)ws_size;
}

// Round 6
// 291.866 us; speedup vs baseline: 2.2453x; 2.2453x over previous
//
#include <hip/hip_runtime.h>
#include <hip/hip_bf16.h>

#define N_NODES 50000
#define N_EDGES 1000000
#define C       128
#define N_REL   8
#define N_SEG   (N_NODES * N_REL)       // 400000
#define KTOT    (N_REL * C + C)         // 1152 = 8 rel chunks + self
#define KC_CNT  (KTOT / 32)             // 36 MFMA k-chunks
#define A_STRIDE 1160                   // 1152 + 8 bf16 pad per row
#define NCHUNK  ((N_SEG + 1023) / 1024) // 391 scan chunks
#define NBLK    (N_NODES / 16)          // 3125 layer blocks
#define FE_BLK  ((N_EDGES + 511) / 512) // 1954 fill edge-blocks (512*1954 >= N_SEG+1 too)

typedef __hip_bfloat16  bf16;
typedef __hip_bfloat162 bf162;
typedef __attribute__((ext_vector_type(8))) short short8;
typedef __attribute__((ext_vector_type(4))) float f32x4;

// ---------------------------------------------------------------- weight fragment index
// B-fragment for mfma_f32_16x16x32_bf16: lane = quad*16 + (n&15) holds
// B[k = kc*32 + quad*8 + j][n], j=0..7 contiguous.
__device__ __forceinline__ size_t frag_index(int k, int n) {
    int nt = n >> 4, n15 = n & 15;
    int kc = k >> 5, quad = (k >> 3) & 3, j = k & 7;
    int lane = quad * 16 + n15;
    return ((size_t)(nt * KC_CNT + kc) * 64 + lane) * 8 + j;
}

// ---------------------------------------------------------------- prep: x->bf16 cvt + seg count
// R16: count atomic's return value IS the rank; packed (rank<<19 | seg) into
// rankseg so fillB never re-reads dst/et (-8 MB). cvt vectorized float4.
#define CVT_BLOCKS ((N_NODES * C / 4) / 256)          // 6250 (exact)
#define CNT_BLOCKS ((N_EDGES + 255) / 256)            // 3907
typedef __attribute__((ext_vector_type(2))) unsigned int uint2v;
__global__ void prep_kernel(const float4* __restrict__ xf, uint2v* __restrict__ xb,
                            const int* __restrict__ dst, const int* __restrict__ et,
                            int* __restrict__ cnt, int* __restrict__ rankseg) {
    int bid = blockIdx.x;
    if (bid < CVT_BLOCKS) {
        int i = bid * 256 + threadIdx.x;
        float4 v = xf[i];
        union { bf162 h; unsigned int u; } c0, c1;
        c0.h = bf162(__float2bfloat16(v.x), __float2bfloat16(v.y));
        c1.h = bf162(__float2bfloat16(v.z), __float2bfloat16(v.w));
        uint2v o; o.x = c0.u; o.y = c1.u;
        xb[i] = o;
    } else {
        int e = (bid - CVT_BLOCKS) * 256 + threadIdx.x;
        if (e < N_EDGES) {
            int seg = dst[e] * N_REL + et[e];
            int r = atomicAdd(&cnt[seg], 1);
            rankseg[e] = (r << 19) | seg;
        }
    }
}

// ---------------------------------------------------------------- scanA: chunk scans + weight repack
// repack1: plain copy (RP_B blocks).  repack2: tiled GEMM W2cat x linW
// (RPT_B blocks of 16x16 output tiles, staged via LDS -> coalesced).
#define RP_B  (KTOT * C / 256)            // 576
#define RPT_B ((KTOT / 16) * (C / 16))    // 72 * 8 = 576
__global__ void scanA_kernel(const int* __restrict__ cnt, int* __restrict__ offs,
                             int* __restrict__ partials,
                             const float* __restrict__ W1, const float* __restrict__ root1,
                             const float* __restrict__ W2, const float* __restrict__ root2,
                             const float* __restrict__ linW,
                             const float* __restrict__ b2, const float* __restrict__ linb,
                             bf16* __restrict__ Bp1, bf16* __restrict__ Bp2,
                             float* __restrict__ b2p) {
    int bid = blockIdx.x;
    int t   = threadIdx.x;
    if (bid < NCHUNK) {
        __shared__ int tot[256];
        int base = bid * 1024 + t * 4;
        int v0 = (base + 0 < N_SEG) ? cnt[base + 0] : 0;
        int v1 = (base + 1 < N_SEG) ? cnt[base + 1] : 0;
        int v2 = (base + 2 < N_SEG) ? cnt[base + 2] : 0;
        int v3 = (base + 3 < N_SEG) ? cnt[base + 3] : 0;
        int tsum = v0 + v1 + v2 + v3;
        tot[t] = tsum;
        __syncthreads();
        for (int d = 1; d < 256; d <<= 1) {
            int x = tot[t];
            int y = (t >= d) ? tot[t - d] : 0;
            __syncthreads();
            tot[t] = x + y;
            __syncthreads();
        }
        int excl = tot[t] - tsum;
        if (base + 0 < N_SEG) offs[base + 0] = excl;
        if (base + 1 < N_SEG) offs[base + 1] = excl + v0;
        if (base + 2 < N_SEG) offs[base + 2] = excl + v0 + v1;
        if (base + 3 < N_SEG) offs[base + 3] = excl + v0 + v1 + v2;
        if (t == 255) partials[bid] = tot[255];
    } else if (bid < NCHUNK + RP_B) {
        int idx = (bid - NCHUNK) * 256 + t;
        int k = idx >> 7, n = idx & 127;
        float val;
        if (k < N_REL * C) val = W1[(size_t)k * C + n];
        else               val = root1[(size_t)(k - N_REL * C) * C + n];
        Bp1[frag_index(k, n)] = __float2bfloat16(val);
    } else if (bid < NCHUNK + RP_B + RPT_B) {
        // ---- tiled repack2: out(k0+ty, n0+tx) = sum_m W2cat[k0+ty][m] * linW[m][n0+tx]
        __shared__ float Wt[16][128];    // 8 KB
        __shared__ float Lt[128][16];    // 8 KB
        int tileid = bid - NCHUNK - RP_B;
        int kt = tileid >> 3;            // 0..71  (k0 = kt*16; 1024 boundary not straddled)
        int n0 = (tileid & 7) * 16;
        int k0 = kt * 16;
        const float* baseW = (k0 < N_REL * C) ? (W2 + (size_t)k0 * C)
                                              : (root2 + (size_t)(k0 - N_REL * C) * C);
#pragma unroll
        for (int r = 0; r < 8; r++) {            // 2048 elems, coalesced
            int idx = t + r * 256;
            Wt[idx >> 7][idx & 127] = baseW[idx];
        }
#pragma unroll
        for (int r = 0; r < 8; r++) {            // 2048 elems: m = idx>>4, n = idx&15
            int idx = t + r * 256;
            Lt[idx >> 4][idx & 15] = linW[(size_t)(idx >> 4) * C + n0 + (idx & 15)];
        }
        __syncthreads();
        int ty = t >> 4, tx = t & 15;
        float acc = 0.f;
#pragma unroll 8
        for (int m = 0; m < 128; m++)
            acc += Wt[ty][m] * Lt[m][tx];
        Bp2[frag_index(k0 + ty, n0 + tx)] = __float2bfloat16(acc);
    } else {
        if (t < 128) {
            float acc = linb[t];
            for (int m = 0; m < C; m++)
                acc += b2[m] * linW[(size_t)m * C + t];
            b2p[t] = acc;
        }
    }
}

// ---------------------------------------------------------------- fillB: edge fill + FINAL offs
// R16: reads rankseg (no dst/et re-read). Writes FINAL CSR directly into the
// dead input buffers: srcs_final over ei.dst, offs_final into the et buffer.
// Both fused layers then read the same final CSR -> no relocation pass.
__global__ void fillB_kernel(const int* __restrict__ src,
                             const int* __restrict__ rankseg,
                             const int* __restrict__ offs_raw,   // scanA output (chunk-local)
                             const int* __restrict__ partials,
                             int* __restrict__ srcs_out,
                             int* __restrict__ offs_final) {
    __shared__ int s[512];
    int t = threadIdx.x;
    int bid = blockIdx.x;
    s[t] = (t < NCHUNK) ? partials[t] : 0;
    __syncthreads();
    for (int d = 1; d < 512; d <<= 1) {
        int x = s[t];
        int y = (t >= d) ? s[t - d] : 0;
        __syncthreads();
        s[t] = x + y;          // inclusive scan
        __syncthreads();
    }
    int e = bid * 512 + t;
    // finalize offsets (grid covers N_SEG+1 <= FE_BLK*512)
    if (e < N_SEG) {
        int chunk = e >> 10;
        offs_final[e] = offs_raw[e] + ((chunk == 0) ? 0 : s[chunk - 1]);
    } else if (e == N_SEG) {
        offs_final[N_SEG] = N_EDGES;
    }
    // place edges
    if (e < N_EDGES) {
        int rs = rankseg[e];
        int seg = rs & 0x7FFFF;
        int r = ((unsigned int)rs) >> 19;
        int chunk = seg >> 10;
        int base = offs_raw[seg] + ((chunk == 0) ? 0 : s[chunk - 1]);
        srcs_out[base + r] = src[e];
    }
}

// ---------------------------------------------------------------- fused layer
// R0-proven body verbatim (73.4 us measured): 16 nodes/block, 512 threads
// (8 waves), wave w owns segments [16w,16w+16), explicit 2-stage gather
// pipeline, LDS offsL. R16: no CSR copy, no RAWOFFS -- plain final offsets.
template <int RELU, int OUT_F32>
__global__ __launch_bounds__(512, 6) void fused_layer(
        const unsigned int* __restrict__ featu,  // [N][64] bf16 pairs
        const int*   __restrict__ offs,          // [N_SEG+1] final
        const int*   __restrict__ srcs,          // [N_EDGES]
        const short8* __restrict__ Bp,           // fragment-packed bf16 weights
        const float* __restrict__ bias,          // [128] fp32
        void* __restrict__ outp)                 // [N][128] fp32 or bf16
{
    __shared__ __align__(16) unsigned int At[16 * (A_STRIDE / 2)];  // bf16 pairs
    __shared__ int offsL[129];
    const int tid  = threadIdx.x;
    const int lane = tid & 63;
    const int w    = tid >> 6;          // 0..7
    const int v0   = blockIdx.x * 16;

    if (tid < 129) offsL[tid] = offs[v0 * 8 + tid];
    if (tid < 64)  At[(tid >> 2) * (A_STRIDE / 2) + 576 + (tid & 3)] = 0u;  // pad pairs

    // self rows -> k range [1024..1151]
    for (int q = tid; q < 16 * 64; q += 512) {
        int node = q >> 6, pch = q & 63;
        At[node * (A_STRIDE / 2) + 512 + pch] = featu[(size_t)(v0 + node) * 64 + pch];
    }
    __syncthreads();

    // ---- aggregation over wave-owned contiguous edge range (16 segments)
    {
        const int segLo = w * 16;
        const int segHi = segLo + 16;
        int curSeg = segLo;
        int segEnd = offsL[curSeg + 1];
        int i      = offsL[segLo];
        const int eend = offsL[segHi];
        float a0 = 0.f, a1 = 0.f;

        unsigned int vals[16];
        bool have = (i + 16 <= eend);
        if (have) {
            const int ib = __builtin_amdgcn_readfirstlane(i);
            int sv[16];
#pragma unroll
            for (int j = 0; j < 16; j++) sv[j] = srcs[ib + j];
#pragma unroll
            for (int j = 0; j < 16; j++) vals[j] = featu[(size_t)sv[j] * 64 + lane];
        }
        while (have) {
            const int inext = i + 16;
            const bool havenext = (inext + 16 <= eend);
            unsigned int vals2[16];
            if (havenext) {                       // prefetch batch k+1 (straight-line)
                const int ib2 = __builtin_amdgcn_readfirstlane(inext);
                int sv2[16];
#pragma unroll
                for (int j = 0; j < 16; j++) sv2[j] = srcs[ib2 + j];
#pragma unroll
                for (int j = 0; j < 16; j++) vals2[j] = featu[(size_t)sv2[j] * 64 + lane];
            }
            // fold batch k
#pragma unroll
            for (int j = 0; j < 16; j++) {
                while (i + j == segEnd) {         // flush finished segment(s)
                    int b = offsL[curSeg];
                    float inv = (segEnd > b) ? 1.0f / (float)(segEnd - b) : 0.0f;
                    union { bf162 h; unsigned int u; } cv;
                    cv.h = bf162(__float2bfloat16(a0 * inv), __float2bfloat16(a1 * inv));
                    At[(curSeg >> 3) * (A_STRIDE / 2) + (curSeg & 7) * 64 + lane] = cv.u;
                    a0 = 0.f; a1 = 0.f;
                    curSeg++;
                    segEnd = offsL[curSeg + 1];
                }
                union { bf162 h; unsigned int u; } uv; uv.u = vals[j];
                a0 += __low2float(uv.h);
                a1 += __high2float(uv.h);
            }
            i = inext;
            have = havenext;
            if (havenext) {
#pragma unroll
                for (int j = 0; j < 16; j++) vals[j] = vals2[j];
            }
        }
        // predicated tail batch (m < 16, wave-uniform)
        {
            int m = eend - i;
            const int ib = __builtin_amdgcn_readfirstlane(i);
            int sv[16];
#pragma unroll
            for (int j = 0; j < 16; j++) if (j < m) sv[j] = srcs[ib + j];
            unsigned int tvals[16];
#pragma unroll
            for (int j = 0; j < 16; j++) if (j < m) tvals[j] = featu[(size_t)sv[j] * 64 + lane];
#pragma unroll
            for (int j = 0; j < 16; j++) {
                if (j < m) {
                    while (i + j == segEnd) {
                        int b = offsL[curSeg];
                        float inv = (segEnd > b) ? 1.0f / (float)(segEnd - b) : 0.0f;
                        union { bf162 h; unsigned int u; } cv;
                        cv.h = bf162(__float2bfloat16(a0 * inv), __float2bfloat16(a1 * inv));
                        At[(curSeg >> 3) * (A_STRIDE / 2) + (curSeg & 7) * 64 + lane] = cv.u;
                        a0 = 0.f; a1 = 0.f;
                        curSeg++;
                        segEnd = offsL[curSeg + 1];
                    }
                    union { bf162 h; unsigned int u; } uv; uv.u = tvals[j];
                    a0 += __low2float(uv.h);
                    a1 += __high2float(uv.h);
                }
            }
        }
        // trailing flushes (last non-empty segment + empty tails)
        while (curSeg < segHi) {
            int b = offsL[curSeg], e2 = offsL[curSeg + 1];
            float inv = (e2 > b) ? 1.0f / (float)(e2 - b) : 0.0f;
            union { bf162 h; unsigned int u; } cv;
            cv.h = bf162(__float2bfloat16(a0 * inv), __float2bfloat16(a1 * inv));
            At[(curSeg >> 3) * (A_STRIDE / 2) + (curSeg & 7) * 64 + lane] = cv.u;
            a0 = 0.f; a1 = 0.f;
            curSeg++;
        }
    }
    __syncthreads();

    // ---- MFMA GEMM: wave w computes N-tile w (cols 16w..16w+15)
    const int quad = lane >> 4, n15 = lane & 15;
    f32x4 acc = {0.f, 0.f, 0.f, 0.f};
    const short* Ash = (const short*)At;

    short8 b0 = Bp[(size_t)(w * KC_CNT) * 64 + lane];
#pragma unroll 4
    for (int kc = 0; kc < KC_CNT; kc++) {
        short8 cb0 = b0;
        if (kc + 1 < KC_CNT)
            b0 = Bp[(size_t)(w * KC_CNT + kc + 1) * 64 + lane];
        short8 a = *reinterpret_cast<const short8*>(Ash + n15 * A_STRIDE + kc * 32 + quad * 8);
        acc = __builtin_amdgcn_mfma_f32_16x16x32_bf16(a, cb0, acc, 0, 0, 0);
    }

    // epilogue: D[m = quad*4 + r][col = w*16 + n15]
    {
        int col = w * 16 + n15;
        float bv = bias[col];
#pragma unroll
        for (int r = 0; r < 4; r++) {
            int m = quad * 4 + r;
            float v = acc[r] + bv;
            if (RELU) v = fmaxf(v, 0.f);
            if (OUT_F32) ((float*)outp)[(size_t)(v0 + m) * C + col] = v;
            else         ((bf16*)outp)[(size_t)(v0 + m) * C + col] = __float2bfloat16(v);
        }
    }
}

// ---------------------------------------------------------------- launch
// fp32 I/O. ZERO d_ws usage. Buffer provenance (R16 layout):
//   d_out      : cnt / offs_t raw / partials / rankseg / xb16 (all scratch,
//                dead before layer 2 overwrites d_out with the final output)
//   ei buffer  : [0..4MB) src (input, dead after fillB);
//                [4..8MB) dst (input, dead after prep) -> srcs_final (fillB)
//   et buffer  : et (input, dead after prep) -> offs_final (fillB)
//   x buffer   : h1 bf16 low (x fp32 dead after cvt); packed weights high
extern "C" void kernel_launch(void* const* d_in, const int* in_sizes, int n_in,
                              void* d_out, int out_size, void* d_ws, size_t ws_size,
                              hipStream_t stream) {
    const float* x     = (const float*)d_in[0];
    const int*   ei    = (const int*)d_in[1];
    const int*   et    = (const int*)d_in[2];
    const float* W1    = (const float*)d_in[3];
    const float* root1 = (const float*)d_in[4];
    const float* b1    = (const float*)d_in[5];
    const float* W2    = (const float*)d_in[6];
    const float* root2 = (const float*)d_in[7];
    const float* b2    = (const float*)d_in[8];
    const float* linW  = (const float*)d_in[9];
    const float* linb  = (const float*)d_in[10];
    const int* src = ei;
    const int* dst = ei + N_EDGES;

    // ---- d_out scratch
    char* ob = (char*)d_out;
    int* cnt_i    = (int*)(ob + 0);          // 1,600,000 B (memset)
    int* offs_t   = (int*)(ob + 1600000);    // 1,600,000 B (raw chunk-local scans)
    int* partials = (int*)(ob + 3200000);    // 1,564 B
    int* rankseg  = (int*)(ob + 3203584);    // 4,000,000 B -> ends 7,203,584
    unsigned int* xb16 = (unsigned int*)(ob + 7203584);  // 256B-aligned; ends 20,003,584 < 25.6 MB

    // ---- final CSR in dead input buffers
    int* srcs_f = (int*)((char*)d_in[1] + 4000000);   // over dst (dead after prep)
    int* offs_f = (int*)d_in[2];                      // over et  (dead after prep); 1.6 MB < 4 MB

    // ---- x buffer: h1 low, weights high
    char* xbuf = (char*)d_in[0];
    unsigned int* h1 = (unsigned int*)xbuf;          // 12.8 MB
    bf16*  Bp1 = (bf16*)(xbuf + 13000192);           // 16B-aligned, 294,912 B
    bf16*  Bp2 = (bf16*)(xbuf + 13295360);           // 294,912 B
    float* b2p = (float*)(xbuf + 13590528);          // 512 B -> ends < 25.6 MB

    float* out = (float*)d_out;

    hipMemsetAsync(cnt_i, 0, 1600000, stream);   // cnt only
    prep_kernel<<<CVT_BLOCKS + CNT_BLOCKS, 256, 0, stream>>>(
        (const float4*)x, (uint2v*)xb16, dst, et, cnt_i, rankseg);
    scanA_kernel<<<NCHUNK + RP_B + RPT_B + 1, 256, 0, stream>>>(
        cnt_i, offs_t, partials, W1, root1, W2, root2, linW, b2, linb,
        Bp1, Bp2, b2p);
    fillB_kernel<<<FE_BLK, 512, 0, stream>>>(
        src, rankseg, offs_t, partials, srcs_f, offs_f);

    fused_layer<1, 0><<<NBLK, 512, 0, stream>>>(
        xb16, offs_f, srcs_f, (const short8*)Bp1, b1, (void*)h1);
    fused_layer<0, 1><<<NBLK, 512, 0, stream>>>(
        h1, offs_f, srcs_f, (const short8*)Bp2, b2p, (void*)out);

    (void)in_sizes; (void)n_in; (void)out_size; (void)d_ws; (void)ws_size;
}